// Round 4
// baseline (211.222 us; speedup 1.0000x reference)
//
#include <hip/hip_runtime.h>
#include <math.h>

#define BDIM 512
#define LDIM 1024
#define DDIM 256
#define NTHREADS 512
#define NWAVES 8
#define SCALE 0.0625f   // 1/sqrt(256)/TEMP

// Fused single-pass cross-attention, dense-compacted streaming.
// R4 change: per-wave CONTIGUOUS chunks of the compacted row list (was
// stride-NWAVES interleave). Each 4-row unrolled iteration reads 4 KB
// contiguous from K and 4 KB contiguous from V -> DRAM page locality is
// guaranteed per-wave instead of relying on cross-wave lockstep.
__global__ __launch_bounds__(NTHREADS, 4)
void fused_cross_attn(const float* __restrict__ Qm, const float* __restrict__ Km,
                      const float* __restrict__ Vm, const int* __restrict__ pad,
                      const float* __restrict__ Wq, const float* __restrict__ bq,
                      const float* __restrict__ Wk, const float* __restrict__ bk,
                      const float* __restrict__ Wv, const float* __restrict__ bv,
                      float* __restrict__ out_ctx, float* __restrict__ out_w) {
  const int b    = blockIdx.x;
  const int tid  = threadIdx.x;
  const int lane = tid & 63;
  const int wave = tid >> 6;          // 0..7

  __shared__ float  qrow_s[DDIM];
  __shared__ float  q_s[DDIM];
  __shared__ float  qt_s[DDIM];
  __shared__ float  e_s[LDIM];        // unnormalized exp(score), 0 for masked
  __shared__ int    p_s[LDIM];        // padding mask
  __shared__ int    idx_s[LDIM];      // compacted unmasked row indices
  __shared__ int    cnt_s[16];
  __shared__ int    base_s[16];
  __shared__ int    nkeep_s;
  __shared__ float  red_s[2][DDIM];
  __shared__ float4 vred_s[NWAVES][64];
  __shared__ float  zred_s[NWAVES];
  __shared__ float  ctxv_s[DDIM];
  __shared__ float  cb_s, invZ_s;

  // ---- Stage 0: preload Q row + mask; zero e_s ----
  if (tid < 64)
    ((float4*)qrow_s)[tid] = ((const float4*)(Qm + (size_t)b * DDIM))[tid];
  if (tid < 256)
    ((int4*)p_s)[tid] = ((const int4*)(pad + (size_t)b * LDIM))[tid];
  e_s[tid] = 0.f;
  e_s[tid + NTHREADS] = 0.f;
  __syncthreads();

  // ---- Stage 0b: compact unmasked indices (ballot + popcount scan) ----
  {
    const int l0 = tid;               // wave w covers chunk w (l = w*64+lane)
    const int l1 = tid + NTHREADS;    // and chunk w+8
    const bool keep0 = (p_s[l0] == 0);
    const bool keep1 = (p_s[l1] == 0);
    const unsigned long long m0 = __ballot(keep0);
    const unsigned long long m1 = __ballot(keep1);
    if (lane == 0) {
      cnt_s[wave]     = __popcll(m0);
      cnt_s[wave + 8] = __popcll(m1);
    }
    __syncthreads();
    if (tid == 0) {
      int s = 0;
#pragma unroll
      for (int c = 0; c < 16; ++c) { base_s[c] = s; s += cnt_s[c]; }
      nkeep_s = s;
    }
    __syncthreads();
    const unsigned long long below = (lane == 0) ? 0ull : (~0ull >> (64 - lane));
    if (keep0) idx_s[base_s[wave]     + __popcll(m0 & below)] = l0;
    if (keep1) idx_s[base_s[wave + 8] + __popcll(m1 & below)] = l1;
  }

  // ---- Stage 1: q[i] = qrow . Wq[i,:] + bq[i] (coalesced row reads) ----
  {
    const float4 q4 = ((const float4*)qrow_s)[lane];
    for (int r = 0; r < DDIM / NWAVES; ++r) {
      const int i = wave * (DDIM / NWAVES) + r;
      float4 w4 = ((const float4*)(Wq + (size_t)i * DDIM))[lane];
      float d = w4.x * q4.x + w4.y * q4.y + w4.z * q4.z + w4.w * q4.w;
#pragma unroll
      for (int o = 32; o; o >>= 1) d += __shfl_xor(d, o, 64);
      if (lane == 0) q_s[i] = d + bq[i];
    }
  }
  __syncthreads();

  // ---- Stage 2: qt[d] = (sum_j q[j]*Wk[j,d])*SCALE ; cb = (q.bk)*SCALE ----
  {
    const int i    = tid & (DDIM - 1);
    const int half = tid >> 8;
    const int j0   = half * (DDIM / 2);
    float p = 0.f;
#pragma unroll 8
    for (int j = 0; j < DDIM / 2; ++j)
      p += q_s[j0 + j] * Wk[(size_t)(j0 + j) * DDIM + i];
    red_s[half][i] = p;
  }
  if (tid < 64) {
    float p = 0.f;
#pragma unroll
    for (int k = 0; k < 4; ++k) p += q_s[tid + 64 * k] * bk[tid + 64 * k];
#pragma unroll
    for (int o = 32; o; o >>= 1) p += __shfl_xor(p, o, 64);
    if (tid == 0) cb_s = p * SCALE;
  }
  __syncthreads();
  if (tid < DDIM) qt_s[tid] = (red_s[0][tid] + red_s[1][tid]) * SCALE;
  __syncthreads();

  // ---- Stage 3: branch-free dense stream, contiguous per-wave chunks ----
  {
    const float  cb    = cb_s;
    const float4 qt4   = ((const float4*)qt_s)[lane];
    const int    nkeep = nkeep_s;
    const int    jbeg  = (nkeep * wave) >> 3;       // contiguous chunk
    const int    jend  = (nkeep * (wave + 1)) >> 3; // wave7 -> nkeep exactly
    const float4* K4 = (const float4*)(Km + (size_t)b * LDIM * DDIM);
    const float4* V4 = (const float4*)(Vm + (size_t)b * LDIM * DDIM);
    float4 acc = {0.f, 0.f, 0.f, 0.f};
    float  zw  = 0.f;
    int j = jbeg;
    for (; j + 4 <= jend; j += 4) {
      const int l0 = idx_s[j + 0];     // consecutive unmasked rows:
      const int l1 = idx_s[j + 1];     // ~4 KB contiguous in K and in V
      const int l2 = idx_s[j + 2];
      const int l3 = idx_s[j + 3];
      float4 k0 = K4[(size_t)l0 * 64 + lane], v0 = V4[(size_t)l0 * 64 + lane];
      float4 k1 = K4[(size_t)l1 * 64 + lane], v1 = V4[(size_t)l1 * 64 + lane];
      float4 k2 = K4[(size_t)l2 * 64 + lane], v2 = V4[(size_t)l2 * 64 + lane];
      float4 k3 = K4[(size_t)l3 * 64 + lane], v3 = V4[(size_t)l3 * 64 + lane];
      float d0 = k0.x*qt4.x + k0.y*qt4.y + k0.z*qt4.z + k0.w*qt4.w;
      float d1 = k1.x*qt4.x + k1.y*qt4.y + k1.z*qt4.z + k1.w*qt4.w;
      float d2 = k2.x*qt4.x + k2.y*qt4.y + k2.z*qt4.z + k2.w*qt4.w;
      float d3 = k3.x*qt4.x + k3.y*qt4.y + k3.z*qt4.z + k3.w*qt4.w;
#pragma unroll
      for (int o = 32; o; o >>= 1) {       // 4 independent reduce chains
        d0 += __shfl_xor(d0, o, 64);
        d1 += __shfl_xor(d1, o, 64);
        d2 += __shfl_xor(d2, o, 64);
        d3 += __shfl_xor(d3, o, 64);
      }
      const float e0 = __expf(d0 + cb);
      const float e1 = __expf(d1 + cb);
      const float e2 = __expf(d2 + cb);
      const float e3 = __expf(d3 + cb);
      if (lane == 0) {
        e_s[l0] = e0; e_s[l1] = e1; e_s[l2] = e2; e_s[l3] = e3;
      }
      acc.x += e0*v0.x + e1*v1.x + e2*v2.x + e3*v3.x;
      acc.y += e0*v0.y + e1*v1.y + e2*v2.y + e3*v3.y;
      acc.z += e0*v0.z + e1*v1.z + e2*v2.z + e3*v3.z;
      acc.w += e0*v0.w + e1*v1.w + e2*v2.w + e3*v3.w;
      zw += e0 + e1 + e2 + e3;
    }
    for (; j < jend; ++j) {               // tail (<= 3 rows)
      const int l = idx_s[j];
      float4 k4 = K4[(size_t)l * 64 + lane];
      float4 v4 = V4[(size_t)l * 64 + lane];
      float d = k4.x*qt4.x + k4.y*qt4.y + k4.z*qt4.z + k4.w*qt4.w;
#pragma unroll
      for (int o = 32; o; o >>= 1) d += __shfl_xor(d, o, 64);
      const float e = __expf(d + cb);
      if (lane == 0) e_s[l] = e;
      acc.x += e*v4.x; acc.y += e*v4.y; acc.z += e*v4.z; acc.w += e*v4.w;
      zw += e;
    }
    vred_s[wave][lane] = acc;
    if (lane == 0) zred_s[wave] = zw;
  }
  __syncthreads();

  // ---- Stage 4: merge per-wave partials; ctxv = acc/Z ----
  if (tid < 64) {
    float4 t = vred_s[0][tid];
    float  Z = zred_s[0];
#pragma unroll
    for (int k = 1; k < NWAVES; ++k) {
      float4 u = vred_s[k][tid];
      t.x += u.x; t.y += u.y; t.z += u.z; t.w += u.w;
      Z += zred_s[k];
    }
    const float inv = 1.0f / Z;
    t.x *= inv; t.y *= inv; t.z *= inv; t.w *= inv;
    ((float4*)ctxv_s)[tid] = t;
    if (tid == 0) invZ_s = inv;
  }
  __syncthreads();

  // ---- Stage 5: weights output (coalesced; masked entries are 0) ----
  {
    const float inv = invZ_s;
    out_w[(size_t)b * LDIM + tid]            = e_s[tid] * inv;
    out_w[(size_t)b * LDIM + tid + NTHREADS] = e_s[tid + NTHREADS] * inv;
  }

  // ---- Stage 6: context[i] = Wv[i,:] . ctxv + bv[i] (coalesced rows) ----
  {
    const float4 c4 = ((const float4*)ctxv_s)[lane];
    for (int r = 0; r < DDIM / NWAVES; ++r) {
      const int i = wave * (DDIM / NWAVES) + r;
      float4 w4 = ((const float4*)(Wv + (size_t)i * DDIM))[lane];
      float d = w4.x * c4.x + w4.y * c4.y + w4.z * c4.z + w4.w * c4.w;
#pragma unroll
      for (int o = 32; o; o >>= 1) d += __shfl_xor(d, o, 64);
      if (lane == 0) red_s[0][i] = d + bv[i];
    }
  }
  __syncthreads();
  if (tid < DDIM)
    out_ctx[(size_t)b * DDIM + tid] = red_s[0][tid];
}

extern "C" void kernel_launch(void* const* d_in, const int* in_sizes, int n_in,
                              void* d_out, int out_size, void* d_ws, size_t ws_size,
                              hipStream_t stream) {
  const float* Q   = (const float*)d_in[0];
  const float* K   = (const float*)d_in[1];
  const float* V   = (const float*)d_in[2];
  const int*   pad = (const int*)d_in[3];
  const float* Wq  = (const float*)d_in[4];
  const float* bq  = (const float*)d_in[5];
  const float* Wk  = (const float*)d_in[6];
  const float* bk  = (const float*)d_in[7];
  const float* Wv  = (const float*)d_in[8];
  const float* bv  = (const float*)d_in[9];

  float* out_ctx = (float*)d_out;                       // (512,256)
  float* out_w   = (float*)d_out + (size_t)BDIM * DDIM; // (512,1,1024)

  fused_cross_attn<<<BDIM, NTHREADS, 0, stream>>>(
      Q, K, V, pad, Wq, bq, Wk, bk, Wv, bv, out_ctx, out_w);
}

// Round 6
// 179.829 us; speedup vs baseline: 1.1746x; 1.1746x over previous
//
#include <hip/hip_runtime.h>
#include <math.h>

#define BDIM 512
#define LDIM 1024
#define DDIM 256
#define NTHREADS 512
#define NWAVES 8
#define SCALE 0.0625f   // 1/sqrt(256)/TEMP

typedef float f32x4 __attribute__((ext_vector_type(4)));  // native vec for nt builtins

// Fused single-pass cross-attention, dense-compacted streaming.
// R6 = R5 intent, fixed types: K/V stream loads NON-TEMPORAL via native
// clang vector type (HIP_vector_type rejected by the builtin); out_w
// stores non-temporal. Structure otherwise identical to R4.
__global__ __launch_bounds__(NTHREADS, 4)
void fused_cross_attn(const float* __restrict__ Qm, const float* __restrict__ Km,
                      const float* __restrict__ Vm, const int* __restrict__ pad,
                      const float* __restrict__ Wq, const float* __restrict__ bq,
                      const float* __restrict__ Wk, const float* __restrict__ bk,
                      const float* __restrict__ Wv, const float* __restrict__ bv,
                      float* __restrict__ out_ctx, float* __restrict__ out_w) {
  const int b    = blockIdx.x;
  const int tid  = threadIdx.x;
  const int lane = tid & 63;
  const int wave = tid >> 6;          // 0..7

  __shared__ float  qrow_s[DDIM];
  __shared__ float  q_s[DDIM];
  __shared__ float  qt_s[DDIM];
  __shared__ float  e_s[LDIM];        // unnormalized exp(score), 0 for masked
  __shared__ int    p_s[LDIM];        // padding mask
  __shared__ int    idx_s[LDIM];      // compacted unmasked row indices
  __shared__ int    cnt_s[16];
  __shared__ int    base_s[16];
  __shared__ int    nkeep_s;
  __shared__ float  red_s[2][DDIM];
  __shared__ f32x4  vred_s[NWAVES][64];
  __shared__ float  zred_s[NWAVES];
  __shared__ float  ctxv_s[DDIM];
  __shared__ float  cb_s, invZ_s;

  // ---- Stage 0: preload Q row + mask; zero e_s ----
  if (tid < 64)
    ((f32x4*)qrow_s)[tid] = ((const f32x4*)(Qm + (size_t)b * DDIM))[tid];
  if (tid < 256)
    ((int4*)p_s)[tid] = ((const int4*)(pad + (size_t)b * LDIM))[tid];
  e_s[tid] = 0.f;
  e_s[tid + NTHREADS] = 0.f;
  __syncthreads();

  // ---- Stage 0b: compact unmasked indices (ballot + popcount scan) ----
  {
    const int l0 = tid;               // wave w covers chunk w (l = w*64+lane)
    const int l1 = tid + NTHREADS;    // and chunk w+8
    const bool keep0 = (p_s[l0] == 0);
    const bool keep1 = (p_s[l1] == 0);
    const unsigned long long m0 = __ballot(keep0);
    const unsigned long long m1 = __ballot(keep1);
    if (lane == 0) {
      cnt_s[wave]     = __popcll(m0);
      cnt_s[wave + 8] = __popcll(m1);
    }
    __syncthreads();
    if (tid == 0) {
      int s = 0;
#pragma unroll
      for (int c = 0; c < 16; ++c) { base_s[c] = s; s += cnt_s[c]; }
      nkeep_s = s;
    }
    __syncthreads();
    const unsigned long long below = (lane == 0) ? 0ull : (~0ull >> (64 - lane));
    if (keep0) idx_s[base_s[wave]     + __popcll(m0 & below)] = l0;
    if (keep1) idx_s[base_s[wave + 8] + __popcll(m1 & below)] = l1;
  }

  // ---- Stage 1: q[i] = qrow . Wq[i,:] + bq[i] (coalesced row reads) ----
  {
    const f32x4 q4 = ((const f32x4*)qrow_s)[lane];
    for (int r = 0; r < DDIM / NWAVES; ++r) {
      const int i = wave * (DDIM / NWAVES) + r;
      f32x4 w4 = ((const f32x4*)(Wq + (size_t)i * DDIM))[lane];
      float d = w4.x * q4.x + w4.y * q4.y + w4.z * q4.z + w4.w * q4.w;
#pragma unroll
      for (int o = 32; o; o >>= 1) d += __shfl_xor(d, o, 64);
      if (lane == 0) q_s[i] = d + bq[i];
    }
  }
  __syncthreads();

  // ---- Stage 2: qt[d] = (sum_j q[j]*Wk[j,d])*SCALE ; cb = (q.bk)*SCALE ----
  {
    const int i    = tid & (DDIM - 1);
    const int half = tid >> 8;
    const int j0   = half * (DDIM / 2);
    float p = 0.f;
#pragma unroll 8
    for (int j = 0; j < DDIM / 2; ++j)
      p += q_s[j0 + j] * Wk[(size_t)(j0 + j) * DDIM + i];
    red_s[half][i] = p;
  }
  if (tid < 64) {
    float p = 0.f;
#pragma unroll
    for (int k = 0; k < 4; ++k) p += q_s[tid + 64 * k] * bk[tid + 64 * k];
#pragma unroll
    for (int o = 32; o; o >>= 1) p += __shfl_xor(p, o, 64);
    if (tid == 0) cb_s = p * SCALE;
  }
  __syncthreads();
  if (tid < DDIM) qt_s[tid] = (red_s[0][tid] + red_s[1][tid]) * SCALE;
  __syncthreads();

  // ---- Stage 3: branch-free dense stream, contiguous per-wave chunks,
  //               NON-TEMPORAL K/V loads ----
  {
    const float  cb    = cb_s;
    const f32x4  qt4   = ((const f32x4*)qt_s)[lane];
    const int    nkeep = nkeep_s;
    const int    jbeg  = (nkeep * wave) >> 3;       // contiguous chunk
    const int    jend  = (nkeep * (wave + 1)) >> 3; // wave7 -> nkeep exactly
    const f32x4* K4 = (const f32x4*)(Km + (size_t)b * LDIM * DDIM);
    const f32x4* V4 = (const f32x4*)(Vm + (size_t)b * LDIM * DDIM);
    f32x4 acc = {0.f, 0.f, 0.f, 0.f};
    float  zw  = 0.f;
    int j = jbeg;
    for (; j + 4 <= jend; j += 4) {
      const int l0 = idx_s[j + 0];     // consecutive unmasked rows
      const int l1 = idx_s[j + 1];
      const int l2 = idx_s[j + 2];
      const int l3 = idx_s[j + 3];
      f32x4 k0 = __builtin_nontemporal_load(&K4[(size_t)l0 * 64 + lane]);
      f32x4 v0 = __builtin_nontemporal_load(&V4[(size_t)l0 * 64 + lane]);
      f32x4 k1 = __builtin_nontemporal_load(&K4[(size_t)l1 * 64 + lane]);
      f32x4 v1 = __builtin_nontemporal_load(&V4[(size_t)l1 * 64 + lane]);
      f32x4 k2 = __builtin_nontemporal_load(&K4[(size_t)l2 * 64 + lane]);
      f32x4 v2 = __builtin_nontemporal_load(&V4[(size_t)l2 * 64 + lane]);
      f32x4 k3 = __builtin_nontemporal_load(&K4[(size_t)l3 * 64 + lane]);
      f32x4 v3 = __builtin_nontemporal_load(&V4[(size_t)l3 * 64 + lane]);
      float d0 = k0.x*qt4.x + k0.y*qt4.y + k0.z*qt4.z + k0.w*qt4.w;
      float d1 = k1.x*qt4.x + k1.y*qt4.y + k1.z*qt4.z + k1.w*qt4.w;
      float d2 = k2.x*qt4.x + k2.y*qt4.y + k2.z*qt4.z + k2.w*qt4.w;
      float d3 = k3.x*qt4.x + k3.y*qt4.y + k3.z*qt4.z + k3.w*qt4.w;
#pragma unroll
      for (int o = 32; o; o >>= 1) {       // 4 independent reduce chains
        d0 += __shfl_xor(d0, o, 64);
        d1 += __shfl_xor(d1, o, 64);
        d2 += __shfl_xor(d2, o, 64);
        d3 += __shfl_xor(d3, o, 64);
      }
      const float e0 = __expf(d0 + cb);
      const float e1 = __expf(d1 + cb);
      const float e2 = __expf(d2 + cb);
      const float e3 = __expf(d3 + cb);
      if (lane == 0) {
        e_s[l0] = e0; e_s[l1] = e1; e_s[l2] = e2; e_s[l3] = e3;
      }
      acc.x += e0*v0.x + e1*v1.x + e2*v2.x + e3*v3.x;
      acc.y += e0*v0.y + e1*v1.y + e2*v2.y + e3*v3.y;
      acc.z += e0*v0.z + e1*v1.z + e2*v2.z + e3*v3.z;
      acc.w += e0*v0.w + e1*v1.w + e2*v2.w + e3*v3.w;
      zw += e0 + e1 + e2 + e3;
    }
    for (; j < jend; ++j) {               // tail (<= 3 rows)
      const int l = idx_s[j];
      f32x4 k4 = __builtin_nontemporal_load(&K4[(size_t)l * 64 + lane]);
      f32x4 v4 = __builtin_nontemporal_load(&V4[(size_t)l * 64 + lane]);
      float d = k4.x*qt4.x + k4.y*qt4.y + k4.z*qt4.z + k4.w*qt4.w;
#pragma unroll
      for (int o = 32; o; o >>= 1) d += __shfl_xor(d, o, 64);
      const float e = __expf(d + cb);
      if (lane == 0) e_s[l] = e;
      acc.x += e*v4.x; acc.y += e*v4.y; acc.z += e*v4.z; acc.w += e*v4.w;
      zw += e;
    }
    vred_s[wave][lane] = acc;
    if (lane == 0) zred_s[wave] = zw;
  }
  __syncthreads();

  // ---- Stage 4: merge per-wave partials; ctxv = acc/Z ----
  if (tid < 64) {
    f32x4 t = vred_s[0][tid];
    float Z = zred_s[0];
#pragma unroll
    for (int k = 1; k < NWAVES; ++k) {
      f32x4 u = vred_s[k][tid];
      t.x += u.x; t.y += u.y; t.z += u.z; t.w += u.w;
      Z += zred_s[k];
    }
    const float inv = 1.0f / Z;
    t.x *= inv; t.y *= inv; t.z *= inv; t.w *= inv;
    ((f32x4*)ctxv_s)[tid] = t;
    if (tid == 0) invZ_s = inv;
  }
  __syncthreads();

  // ---- Stage 5: weights output (coalesced, non-temporal) ----
  {
    const float inv = invZ_s;
    __builtin_nontemporal_store(e_s[tid] * inv,
                                &out_w[(size_t)b * LDIM + tid]);
    __builtin_nontemporal_store(e_s[tid + NTHREADS] * inv,
                                &out_w[(size_t)b * LDIM + tid + NTHREADS]);
  }

  // ---- Stage 6: context[i] = Wv[i,:] . ctxv + bv[i] (coalesced rows) ----
  {
    const f32x4 c4 = ((const f32x4*)ctxv_s)[lane];
    for (int r = 0; r < DDIM / NWAVES; ++r) {
      const int i = wave * (DDIM / NWAVES) + r;
      f32x4 w4 = ((const f32x4*)(Wv + (size_t)i * DDIM))[lane];
      float d = w4.x * c4.x + w4.y * c4.y + w4.z * c4.z + w4.w * c4.w;
#pragma unroll
      for (int o = 32; o; o >>= 1) d += __shfl_xor(d, o, 64);
      if (lane == 0) red_s[0][i] = d + bv[i];
    }
  }
  __syncthreads();
  if (tid < DDIM)
    out_ctx[(size_t)b * DDIM + tid] = red_s[0][tid];
}

extern "C" void kernel_launch(void* const* d_in, const int* in_sizes, int n_in,
                              void* d_out, int out_size, void* d_ws, size_t ws_size,
                              hipStream_t stream) {
  const float* Q   = (const float*)d_in[0];
  const float* K   = (const float*)d_in[1];
  const float* V   = (const float*)d_in[2];
  const int*   pad = (const int*)d_in[3];
  const float* Wq  = (const float*)d_in[4];
  const float* bq  = (const float*)d_in[5];
  const float* Wk  = (const float*)d_in[6];
  const float* bk  = (const float*)d_in[7];
  const float* Wv  = (const float*)d_in[8];
  const float* bv  = (const float*)d_in[9];

  float* out_ctx = (float*)d_out;                       // (512,256)
  float* out_w   = (float*)d_out + (size_t)BDIM * DDIM; // (512,1,1024)

  fused_cross_attn<<<BDIM, NTHREADS, 0, stream>>>(
      Q, K, V, pad, Wq, bq, Wk, bk, Wv, bv, out_ctx, out_w);
}

// Round 7
// 171.102 us; speedup vs baseline: 1.2345x; 1.0510x over previous
//
#include <hip/hip_runtime.h>
#include <math.h>

#define BDIM 512
#define LDIM 1024
#define DDIM 256
#define NTHREADS 512
#define NWAVES 8
#define SCALE 0.0625f   // 1/sqrt(256)/TEMP

typedef float f32x4 __attribute__((ext_vector_type(4)));  // native vec for nt builtins

// Fused single-pass cross-attention, dense-compacted streaming.
// R7 change (single-variable vs R6): per-wave chunk processed in TWO
// single-tensor sub-passes (K-dots then V-accumulate via e_s) instead of
// interleaved K/V rows -> one clean sequential stream per wave per phase
// (tests the concurrent-stream-count / DRAM row-locality theory).
__global__ __launch_bounds__(NTHREADS, 4)
void fused_cross_attn(const float* __restrict__ Qm, const float* __restrict__ Km,
                      const float* __restrict__ Vm, const int* __restrict__ pad,
                      const float* __restrict__ Wq, const float* __restrict__ bq,
                      const float* __restrict__ Wk, const float* __restrict__ bk,
                      const float* __restrict__ Wv, const float* __restrict__ bv,
                      float* __restrict__ out_ctx, float* __restrict__ out_w) {
  const int b    = blockIdx.x;
  const int tid  = threadIdx.x;
  const int lane = tid & 63;
  const int wave = tid >> 6;          // 0..7

  __shared__ float  qrow_s[DDIM];
  __shared__ float  q_s[DDIM];
  __shared__ float  qt_s[DDIM];
  __shared__ float  e_s[LDIM];        // unnormalized exp(score), 0 for masked
  __shared__ int    p_s[LDIM];        // padding mask
  __shared__ int    idx_s[LDIM];      // compacted unmasked row indices
  __shared__ int    cnt_s[16];
  __shared__ int    base_s[16];
  __shared__ int    nkeep_s;
  __shared__ float  red_s[2][DDIM];
  __shared__ f32x4  vred_s[NWAVES][64];
  __shared__ float  zred_s[NWAVES];
  __shared__ float  ctxv_s[DDIM];
  __shared__ float  cb_s, invZ_s;

  // ---- Stage 0: preload Q row + mask; zero e_s ----
  if (tid < 64)
    ((f32x4*)qrow_s)[tid] = ((const f32x4*)(Qm + (size_t)b * DDIM))[tid];
  if (tid < 256)
    ((int4*)p_s)[tid] = ((const int4*)(pad + (size_t)b * LDIM))[tid];
  e_s[tid] = 0.f;
  e_s[tid + NTHREADS] = 0.f;
  __syncthreads();

  // ---- Stage 0b: compact unmasked indices (ballot + popcount scan) ----
  {
    const int l0 = tid;               // wave w covers chunk w (l = w*64+lane)
    const int l1 = tid + NTHREADS;    // and chunk w+8
    const bool keep0 = (p_s[l0] == 0);
    const bool keep1 = (p_s[l1] == 0);
    const unsigned long long m0 = __ballot(keep0);
    const unsigned long long m1 = __ballot(keep1);
    if (lane == 0) {
      cnt_s[wave]     = __popcll(m0);
      cnt_s[wave + 8] = __popcll(m1);
    }
    __syncthreads();
    if (tid == 0) {
      int s = 0;
#pragma unroll
      for (int c = 0; c < 16; ++c) { base_s[c] = s; s += cnt_s[c]; }
      nkeep_s = s;
    }
    __syncthreads();
    const unsigned long long below = (lane == 0) ? 0ull : (~0ull >> (64 - lane));
    if (keep0) idx_s[base_s[wave]     + __popcll(m0 & below)] = l0;
    if (keep1) idx_s[base_s[wave + 8] + __popcll(m1 & below)] = l1;
  }

  // ---- Stage 1: q[i] = qrow . Wq[i,:] + bq[i] (coalesced row reads) ----
  {
    const f32x4 q4 = ((const f32x4*)qrow_s)[lane];
    for (int r = 0; r < DDIM / NWAVES; ++r) {
      const int i = wave * (DDIM / NWAVES) + r;
      f32x4 w4 = ((const f32x4*)(Wq + (size_t)i * DDIM))[lane];
      float d = w4.x * q4.x + w4.y * q4.y + w4.z * q4.z + w4.w * q4.w;
#pragma unroll
      for (int o = 32; o; o >>= 1) d += __shfl_xor(d, o, 64);
      if (lane == 0) q_s[i] = d + bq[i];
    }
  }
  __syncthreads();

  // ---- Stage 2: qt[d] = (sum_j q[j]*Wk[j,d])*SCALE ; cb = (q.bk)*SCALE ----
  {
    const int i    = tid & (DDIM - 1);
    const int half = tid >> 8;
    const int j0   = half * (DDIM / 2);
    float p = 0.f;
#pragma unroll 8
    for (int j = 0; j < DDIM / 2; ++j)
      p += q_s[j0 + j] * Wk[(size_t)(j0 + j) * DDIM + i];
    red_s[half][i] = p;
  }
  if (tid < 64) {
    float p = 0.f;
#pragma unroll
    for (int k = 0; k < 4; ++k) p += q_s[tid + 64 * k] * bk[tid + 64 * k];
#pragma unroll
    for (int o = 32; o; o >>= 1) p += __shfl_xor(p, o, 64);
    if (tid == 0) cb_s = p * SCALE;
  }
  __syncthreads();
  if (tid < DDIM) qt_s[tid] = (red_s[0][tid] + red_s[1][tid]) * SCALE;
  __syncthreads();

  // ---- Stage 3: two single-tensor sub-passes per wave chunk ----
  {
    const float  cb    = cb_s;
    const f32x4  qt4   = ((const f32x4*)qt_s)[lane];
    const int    nkeep = nkeep_s;
    const int    jbeg  = (nkeep * wave) >> 3;       // contiguous chunk
    const int    jend  = (nkeep * (wave + 1)) >> 3; // wave7 -> nkeep exactly
    const f32x4* K4 = (const f32x4*)(Km + (size_t)b * LDIM * DDIM);
    const f32x4* V4 = (const f32x4*)(Vm + (size_t)b * LDIM * DDIM);
    f32x4 acc = {0.f, 0.f, 0.f, 0.f};
    float  zw  = 0.f;

    // -- Phase 1: K stream only: scores -> e_s, Z partial --
    int j = jbeg;
    for (; j + 4 <= jend; j += 4) {
      const int l0 = idx_s[j + 0];
      const int l1 = idx_s[j + 1];
      const int l2 = idx_s[j + 2];
      const int l3 = idx_s[j + 3];
      f32x4 k0 = __builtin_nontemporal_load(&K4[(size_t)l0 * 64 + lane]);
      f32x4 k1 = __builtin_nontemporal_load(&K4[(size_t)l1 * 64 + lane]);
      f32x4 k2 = __builtin_nontemporal_load(&K4[(size_t)l2 * 64 + lane]);
      f32x4 k3 = __builtin_nontemporal_load(&K4[(size_t)l3 * 64 + lane]);
      float d0 = k0.x*qt4.x + k0.y*qt4.y + k0.z*qt4.z + k0.w*qt4.w;
      float d1 = k1.x*qt4.x + k1.y*qt4.y + k1.z*qt4.z + k1.w*qt4.w;
      float d2 = k2.x*qt4.x + k2.y*qt4.y + k2.z*qt4.z + k2.w*qt4.w;
      float d3 = k3.x*qt4.x + k3.y*qt4.y + k3.z*qt4.z + k3.w*qt4.w;
#pragma unroll
      for (int o = 32; o; o >>= 1) {
        d0 += __shfl_xor(d0, o, 64);
        d1 += __shfl_xor(d1, o, 64);
        d2 += __shfl_xor(d2, o, 64);
        d3 += __shfl_xor(d3, o, 64);
      }
      const float e0 = __expf(d0 + cb);
      const float e1 = __expf(d1 + cb);
      const float e2 = __expf(d2 + cb);
      const float e3 = __expf(d3 + cb);
      if (lane == 0) {
        e_s[l0] = e0; e_s[l1] = e1; e_s[l2] = e2; e_s[l3] = e3;
      }
      zw += e0 + e1 + e2 + e3;
    }
    for (; j < jend; ++j) {
      const int l = idx_s[j];
      f32x4 k4 = __builtin_nontemporal_load(&K4[(size_t)l * 64 + lane]);
      float d = k4.x*qt4.x + k4.y*qt4.y + k4.z*qt4.z + k4.w*qt4.w;
#pragma unroll
      for (int o = 32; o; o >>= 1) d += __shfl_xor(d, o, 64);
      const float e = __expf(d + cb);
      if (lane == 0) e_s[l] = e;
      zw += e;
    }

    // -- Phase 2: V stream only: acc += e * V row (e from LDS) --
    j = jbeg;
    for (; j + 4 <= jend; j += 4) {
      const int l0 = idx_s[j + 0];
      const int l1 = idx_s[j + 1];
      const int l2 = idx_s[j + 2];
      const int l3 = idx_s[j + 3];
      f32x4 v0 = __builtin_nontemporal_load(&V4[(size_t)l0 * 64 + lane]);
      f32x4 v1 = __builtin_nontemporal_load(&V4[(size_t)l1 * 64 + lane]);
      f32x4 v2 = __builtin_nontemporal_load(&V4[(size_t)l2 * 64 + lane]);
      f32x4 v3 = __builtin_nontemporal_load(&V4[(size_t)l3 * 64 + lane]);
      const float e0 = e_s[l0];
      const float e1 = e_s[l1];
      const float e2 = e_s[l2];
      const float e3 = e_s[l3];
      acc.x += e0*v0.x + e1*v1.x + e2*v2.x + e3*v3.x;
      acc.y += e0*v0.y + e1*v1.y + e2*v2.y + e3*v3.y;
      acc.z += e0*v0.z + e1*v1.z + e2*v2.z + e3*v3.z;
      acc.w += e0*v0.w + e1*v1.w + e2*v2.w + e3*v3.w;
    }
    for (; j < jend; ++j) {
      const int l = idx_s[j];
      f32x4 v4 = __builtin_nontemporal_load(&V4[(size_t)l * 64 + lane]);
      const float e = e_s[l];
      acc.x += e*v4.x; acc.y += e*v4.y; acc.z += e*v4.z; acc.w += e*v4.w;
    }

    vred_s[wave][lane] = acc;
    if (lane == 0) zred_s[wave] = zw;
  }
  __syncthreads();

  // ---- Stage 4: merge per-wave partials; ctxv = acc/Z ----
  if (tid < 64) {
    f32x4 t = vred_s[0][tid];
    float Z = zred_s[0];
#pragma unroll
    for (int k = 1; k < NWAVES; ++k) {
      f32x4 u = vred_s[k][tid];
      t.x += u.x; t.y += u.y; t.z += u.z; t.w += u.w;
      Z += zred_s[k];
    }
    const float inv = 1.0f / Z;
    t.x *= inv; t.y *= inv; t.z *= inv; t.w *= inv;
    ((f32x4*)ctxv_s)[tid] = t;
    if (tid == 0) invZ_s = inv;
  }
  __syncthreads();

  // ---- Stage 5: weights output (coalesced, non-temporal) ----
  {
    const float inv = invZ_s;
    __builtin_nontemporal_store(e_s[tid] * inv,
                                &out_w[(size_t)b * LDIM + tid]);
    __builtin_nontemporal_store(e_s[tid + NTHREADS] * inv,
                                &out_w[(size_t)b * LDIM + tid + NTHREADS]);
  }

  // ---- Stage 6: context[i] = Wv[i,:] . ctxv + bv[i] (coalesced rows) ----
  {
    const f32x4 c4 = ((const f32x4*)ctxv_s)[lane];
    for (int r = 0; r < DDIM / NWAVES; ++r) {
      const int i = wave * (DDIM / NWAVES) + r;
      f32x4 w4 = ((const f32x4*)(Wv + (size_t)i * DDIM))[lane];
      float d = w4.x * c4.x + w4.y * c4.y + w4.z * c4.z + w4.w * c4.w;
#pragma unroll
      for (int o = 32; o; o >>= 1) d += __shfl_xor(d, o, 64);
      if (lane == 0) red_s[0][i] = d + bv[i];
    }
  }
  __syncthreads();
  if (tid < DDIM)
    out_ctx[(size_t)b * DDIM + tid] = red_s[0][tid];
}

extern "C" void kernel_launch(void* const* d_in, const int* in_sizes, int n_in,
                              void* d_out, int out_size, void* d_ws, size_t ws_size,
                              hipStream_t stream) {
  const float* Q   = (const float*)d_in[0];
  const float* K   = (const float*)d_in[1];
  const float* V   = (const float*)d_in[2];
  const int*   pad = (const int*)d_in[3];
  const float* Wq  = (const float*)d_in[4];
  const float* bq  = (const float*)d_in[5];
  const float* Wk  = (const float*)d_in[6];
  const float* bk  = (const float*)d_in[7];
  const float* Wv  = (const float*)d_in[8];
  const float* bv  = (const float*)d_in[9];

  float* out_ctx = (float*)d_out;                       // (512,256)
  float* out_w   = (float*)d_out + (size_t)BDIM * DDIM; // (512,1,1024)

  fused_cross_attn<<<BDIM, NTHREADS, 0, stream>>>(
      Q, K, V, pad, Wq, bq, Wk, bk, Wv, bv, out_ctx, out_w);
}